// Round 1
// baseline (285.926 us; speedup 1.0000x reference)
//
#include <hip/hip_runtime.h>

// Problem constants (from reference)
#define D_MODEL 1024
#define NB      8          // batch N
#define SLEN    4096       // sequence length S
#define D4      (D_MODEL/4)   // 256 float4 per row
#define ROWS_PER_BLK 32
#define CHUNKS  (SLEN / ROWS_PER_BLK)   // 128 chunks per batch

// Kernel 1: Vsum[n][j] = sum_s V[n][s][j].
// grid = NB * CHUNKS blocks, 256 threads. Each block: 32 full rows, thread t
// owns columns 4t..4t+3 (float4) -> perfectly coalesced 4 KiB/row reads.
// Partial sums via atomicAdd into pre-zeroed Vsum.
__global__ __launch_bounds__(256) void vsum_kernel(
    const float* __restrict__ V, float* __restrict__ Vsum) {
    const int n     = blockIdx.x / CHUNKS;
    const int chunk = blockIdx.x % CHUNKS;
    const int t     = threadIdx.x;

    const float4* Vb = (const float4*)(V + (size_t)n * SLEN * D_MODEL);
    const size_t base = (size_t)chunk * ROWS_PER_BLK * D4 + t;

    float4 acc = make_float4(0.f, 0.f, 0.f, 0.f);
#pragma unroll 8
    for (int r = 0; r < ROWS_PER_BLK; ++r) {
        float4 x = Vb[base + (size_t)r * D4];
        acc.x += x.x; acc.y += x.y; acc.z += x.z; acc.w += x.w;
    }
    float* dst = Vsum + (size_t)n * D_MODEL + t * 4;
    atomicAdd(dst + 0, acc.x);
    atomicAdd(dst + 1, acc.y);
    atomicAdd(dst + 2, acc.z);
    atomicAdd(dst + 3, acc.w);
}

// Kernel 2/3: y[n][i] = sum_j x[n][j] * W[i][j] + bias_scale * b[i]
// One wave (64 lanes) per output column i, all 8 batches together so the
// W row (4 KiB) is read once. float4 weight loads, shuffle reduction.
__global__ __launch_bounds__(64) void gemv8_kernel(
    const float* __restrict__ X,     // [NB][D_MODEL]
    const float* __restrict__ W,     // [D_MODEL][D_MODEL], row i = output i
    const float* __restrict__ b,     // [D_MODEL]
    float* __restrict__ Y,           // [NB][D_MODEL]
    float bias_scale) {
    const int i    = blockIdx.x;
    const int lane = threadIdx.x;

    const float4* Wr = (const float4*)(W + (size_t)i * D_MODEL);
    const float4* Xv = (const float4*)X;

    float acc[NB];
#pragma unroll
    for (int n = 0; n < NB; ++n) acc[n] = 0.f;

#pragma unroll
    for (int g = lane; g < D4; g += 64) {   // 4 iterations
        float4 w = Wr[g];
#pragma unroll
        for (int n = 0; n < NB; ++n) {
            float4 x = Xv[n * D4 + g];
            acc[n] += w.x * x.x + w.y * x.y + w.z * x.z + w.w * x.w;
        }
    }

#pragma unroll
    for (int n = 0; n < NB; ++n) {
        float v = acc[n];
#pragma unroll
        for (int off = 32; off > 0; off >>= 1) v += __shfl_down(v, off);
        if (lane == 0) Y[(size_t)n * D_MODEL + i] = v + bias_scale * b[i];
    }
}

extern "C" void kernel_launch(void* const* d_in, const int* in_sizes, int n_in,
                              void* d_out, int out_size, void* d_ws, size_t ws_size,
                              hipStream_t stream) {
    // Input order: Q, K, V, Wq, bq, Wk, bk, Wv, bv, Wo, bo
    const float* V  = (const float*)d_in[2];
    const float* Wv = (const float*)d_in[7];
    const float* bv = (const float*)d_in[8];
    const float* Wo = (const float*)d_in[9];
    const float* bo = (const float*)d_in[10];
    float* out = (float*)d_out;

    // Workspace layout: Vsum [NB*D_MODEL] floats, vproj [NB*D_MODEL] floats
    float* Vsum  = (float*)d_ws;
    float* vproj = Vsum + NB * D_MODEL;

    // Zero the atomic accumulation target (ws is re-poisoned each call).
    hipMemsetAsync(Vsum, 0, NB * D_MODEL * sizeof(float), stream);

    // 1) column-sum of V over the sequence dimension (the 128 MiB read)
    vsum_kernel<<<NB * CHUNKS, 256, 0, stream>>>(V, Vsum);

    // 2) vproj = Vsum @ Wv.T + S*bv   (softmax over size-1 axis == all-ones)
    gemv8_kernel<<<D_MODEL, 64, 0, stream>>>(Vsum, Wv, bv, vproj, (float)SLEN);

    // 3) out = vproj @ Wo.T + bo
    gemv8_kernel<<<D_MODEL, 64, 0, stream>>>(vproj, Wo, bo, out, 1.0f);
}

// Round 3
// 281.427 us; speedup vs baseline: 1.0160x; 1.0160x over previous
//
#include <hip/hip_runtime.h>

// Problem constants (from reference)
#define D_MODEL 1024
#define NB      8                       // batch N
#define SLEN    4096                    // sequence length S
#define D4      (D_MODEL / 4)           // 256 float4 per row
#define GROUPS  64                      // partial-sum groups per batch
#define ROWS_PER_GROUP (SLEN / GROUPS)  // 64 rows per block in phase 1
#define NBLOCKS (NB * GROUPS)           // 512 blocks = 2 per CU

// Phase 1: atomic-free partial column sums of V.
// Block b = (n, g): sums 64 full rows, thread t owns float4 column t.
// Perfectly coalesced 4 KiB-wide row reads; writes a private 4 KiB slice.
__global__ __launch_bounds__(256) void vsum_partial_kernel(
    const float* __restrict__ V, float4* __restrict__ partials) {
    const int b = blockIdx.x;
    const int t = threadIdx.x;
    const int n = b >> 6;
    const int g = b & 63;

    const float4* Vb = (const float4*)(V + (size_t)n * SLEN * D_MODEL);
    const size_t base = (size_t)g * ROWS_PER_GROUP * D4 + t;

    float4 acc = make_float4(0.f, 0.f, 0.f, 0.f);
#pragma unroll 8
    for (int r = 0; r < ROWS_PER_GROUP; ++r) {
        float4 x = Vb[base + (size_t)r * D4];
        acc.x += x.x; acc.y += x.y; acc.z += x.z; acc.w += x.w;
    }
    partials[(size_t)b * D4 + t] = acc;
}

// Phase 2: reduce 64 partials per batch -> Vsum. 8 blocks (one per batch),
// thread t owns float4 column t; 64 independent 16 B loads -> deep MLP,
// all L2-resident (2 MiB total).
__global__ __launch_bounds__(256) void vsum_reduce_kernel(
    const float4* __restrict__ partials, float4* __restrict__ Vsum) {
    const int n = blockIdx.x;
    const int t = threadIdx.x;
    float4 acc = make_float4(0.f, 0.f, 0.f, 0.f);
#pragma unroll 8
    for (int g = 0; g < GROUPS; ++g) {
        float4 x = partials[((size_t)n * GROUPS + g) * D4 + t];
        acc.x += x.x; acc.y += x.y; acc.z += x.z; acc.w += x.w;
    }
    Vsum[(size_t)n * D4 + t] = acc;
}

// Phases 3/4: y[n][i] = sum_j x[n][j]*W[i][j] + bias_scale*b[i].
// 256 blocks x 256 threads; each wave handles one output column i for all 8
// batches (W row read once). float4 loads, shuffle reduction.
__global__ __launch_bounds__(256) void gemv8_kernel(
    const float4* __restrict__ X,    // [NB][D4]
    const float*  __restrict__ W,    // [D][D], row i = output i
    const float*  __restrict__ bvec, // [D]
    float* __restrict__ Y,           // [NB][D]
    float bias_scale) {
    const int t    = threadIdx.x;
    const int wv   = t >> 6;
    const int lane = t & 63;
    const int i    = blockIdx.x * 4 + wv;

    const float4* Wr = (const float4*)(W + (size_t)i * D_MODEL);

    float acc[NB];
#pragma unroll
    for (int n = 0; n < NB; ++n) acc[n] = 0.f;

#pragma unroll
    for (int g = lane; g < D4; g += 64) {   // 4 iterations
        float4 w = Wr[g];
#pragma unroll
        for (int n = 0; n < NB; ++n) {
            float4 x = X[n * D4 + g];
            acc[n] += w.x * x.x + w.y * x.y + w.z * x.z + w.w * x.w;
        }
    }

#pragma unroll
    for (int n = 0; n < NB; ++n) {
        float v = acc[n];
#pragma unroll
        for (int off = 32; off > 0; off >>= 1) v += __shfl_down(v, off);
        if (lane == 0) Y[(size_t)n * D_MODEL + i] = v + bias_scale * bvec[i];
    }
}

extern "C" void kernel_launch(void* const* d_in, const int* in_sizes, int n_in,
                              void* d_out, int out_size, void* d_ws, size_t ws_size,
                              hipStream_t stream) {
    // Input order: Q, K, V, Wq, bq, Wk, bk, Wv, bv, Wo, bo
    // softmax over a size-1 axis == 1.0, so Q/K/Wq/bq/Wk/bk are dead:
    //   out = ((sum_s V[n,s,:]) @ Wv.T + S*bv) @ Wo.T + bo
    const float* V  = (const float*)d_in[2];
    const float* Wv = (const float*)d_in[7];
    const float* bv = (const float*)d_in[8];
    const float* Wo = (const float*)d_in[9];
    const float* bo = (const float*)d_in[10];
    float* out = (float*)d_out;

    // Workspace: partials [NBLOCKS][D4] f4 (2 MiB), Vsum [NB][D4], vproj [NB][D4]
    float4* partials = (float4*)d_ws;
    float4* Vsum     = partials + (size_t)NBLOCKS * D4;
    float4* vproj    = Vsum + NB * D4;

    vsum_partial_kernel<<<NBLOCKS, 256, 0, stream>>>(V, partials);
    vsum_reduce_kernel<<<NB, 256, 0, stream>>>(partials, Vsum);
    gemv8_kernel<<<D_MODEL / 4, 256, 0, stream>>>(Vsum, Wv, bv, (float*)vproj,
                                                  (float)SLEN);
    gemv8_kernel<<<D_MODEL / 4, 256, 0, stream>>>(vproj, Wo, bo, out, 1.0f);
}